// Round 9
// baseline (114.267 us; speedup 1.0000x reference)
//
#include <hip/hip_runtime.h>

// out: 4 tensors (32, 20, 14, 14, 14, 14) fp32 concatenated (p = 0..3).
// R8: ONE chunk per block. Block -> (p, n, q, d2); writes a single contiguous
// 10,976 B chunk of tensor p. Blocks are XCD-remapped so each XCD sweeps one
// contiguous ~197 MB range of the output in ascending order (1 window/XCD).
//   out_p[d3][ps] = F[d3][ps] * G[d3][ps]           for this block's (i,j):
//   F = A[d3,d4]*B[d3,d5];  A = 0.5*cor_i[0,pc]*cor_i[1+q,pc]*cor_i[23+d4,pc]
//   B = cor_i[37+d5,pc];    G = T[ps]*cen_j[37+d3,ps]
//   T[ps] = cen_j[0,ps]*cen_j[1+q,ps]*cen_j[23+d2,ps]
// p0=(cor1,cen1) p1=(cor2,cen1) p2=(cor1,cen2) p3=(cor2,cen2)

#define S_PER 24586240u            // 32*20*14^4 elements per tensor
#define TSTRIDE (51 * 196)
#define N_STRIDE (204 * 196)
#define NCHUNK 35840u              // 4 * 32*20*14
#define NXCD 8u
#define CHUNK_PER_XCD (NCHUNK / NXCD)   // 4480

__global__ __launch_bounds__(256) void plnet_kernel(const float* __restrict__ in,
                                                    float* __restrict__ out) {
    __shared__ __align__(16) float sT[196];
    __shared__ float sA[196];      // [d3*14 + d4]
    __shared__ float sB[196];      // [d3*14 + d5]

    // XCD-contiguous remap over the flat chunk index of the WHOLE output.
    const unsigned raw = blockIdx.x;
    const unsigned cid = (raw % NXCD) * CHUNK_PER_XCD + raw / NXCD;

    const unsigned p  = cid / 8960u;       // tensor index 0..3
    const unsigned b  = cid % 8960u;       // (n*20+q)*14 + d2
    const unsigned d2 = b % 14u;
    const unsigned nq = b / 14u;
    const unsigned q  = nq % 20u;
    const unsigned n  = nq / 20u;
    const unsigned i  = p & 1u;            // corner select
    const unsigned j  = p >> 1;            // center select

    const float* g   = in + (size_t)n * N_STRIDE;
    const float* cor = g + (size_t)i * TSTRIDE;
    const float* cen = g + (size_t)(2u + j) * TSTRIDE;

    const unsigned tid = threadIdx.x;

    // ---- Prologue: 3 small LDS tables, one barrier ----
    if (tid < 196u) {
        const unsigned ps = tid;
        sT[ps] = cen[ps] * cen[(1u + q) * 196u + ps] * cen[(23u + d2) * 196u + ps];
        const unsigned d3 = ps / 14u;
        const unsigned k  = ps - d3 * 14u;
        const unsigned pc = d2 * 14u + d3;
        sA[ps] = 0.5f * cor[pc] * cor[(1u + q) * 196u + pc] * cor[(23u + k) * 196u + pc];
        sB[ps] = cor[(37u + k) * 196u + pc];
    }
    __syncthreads();

    // ---- Main: 686 float4 items -> one contiguous 10,976 B store stream ----
    float4* o = (float4*)(out + (size_t)p * S_PER + (size_t)b * 2744u);

    for (unsigned c = tid; c < 686u; c += 256u) {
        const unsigned d3 = c / 49u;
        const unsigned f  = c - d3 * 49u;
        const unsigned e  = 4u * f;          // ps of first element

        const float4 v = *(const float4*)&cen[(37u + d3) * 196u + e];
        const float4 t = *(const float4*)&sT[e];
        const float4 G = make_float4(t.x * v.x, t.y * v.y, t.z * v.z, t.w * v.w);

        unsigned d4 = e / 14u;
        unsigned d5 = e - d4 * 14u;
        float F[4];
#pragma unroll
        for (int l = 0; l < 4; ++l) {
            F[l] = sA[d3 * 14u + d4] * sB[d3 * 14u + d5];
            ++d5;
            const unsigned carry = (d5 == 14u);
            d4 += carry;
            d5 = carry ? 0u : d5;
        }

        o[c] = make_float4(F[0] * G.x, F[1] * G.y, F[2] * G.z, F[3] * G.w);
    }
}

extern "C" void kernel_launch(void* const* d_in, const int* in_sizes, int n_in,
                              void* d_out, int out_size, void* d_ws, size_t ws_size,
                              hipStream_t stream) {
    const float* in = (const float*)d_in[0];
    float* out = (float*)d_out;
    dim3 grid(NCHUNK);             // one block per (tensor, n, q, d2) chunk
    dim3 block(256);
    plnet_kernel<<<grid, block, 0, stream>>>(in, out);
}

// Round 10
// 92.508 us; speedup vs baseline: 1.2352x; 1.2352x over previous
//
#include <hip/hip_runtime.h>

// out: 4 tensors (32, 20, 14, 14, 14, 14) fp32 concatenated.
// Block = (n, q, d2); writes 4 contiguous 10,976 B chunks (one per tensor).
// R9 = R6 + fully-materialized F/G LDS tables -> main loop is LDS+VALU+store ONLY.
//   out_p(i,j)[d3][ps] = F_i[d3][ps] * G_j[d3][ps]
//   F_i[d3][ps=d4*14+d5] = A_i[d3,d4] * B_i[d3,d5]
//     A_i[d3,d4] = 0.5*cor_i[0,pc]*cor_i[1+q,pc]*cor_i[23+d4,pc],  pc=d2*14+d3
//     B_i[d3,d5] = cor_i[37+d5,pc]
//   G_j[d3][ps] = T_j[ps] * cen_j[37+d3,ps]
//     T_j[ps]   = cen_j[0,ps]*cen_j[1+q,ps]*cen_j[23+d2,ps]
// p1=F1*G1  p2=F2*G1  p3=F1*G2  p4=F2*G2

#define S_PER 24586240u            // 32*20*14^4 elements per tensor
#define TSTRIDE (51 * 196)
#define N_STRIDE (204 * 196)
#define NBLK 8960u                 // 32*20*14
#define NXCD 8u
#define BLK_PER_XCD (NBLK / NXCD)  // 1120

__global__ __launch_bounds__(256) void plnet_kernel(const float* __restrict__ in,
                                                    float* __restrict__ out) {
    __shared__ __align__(16) float sT1[196], sT2[196];
    __shared__ float sA1[196], sA2[196];       // [d3*14 + d4]
    __shared__ float sB1[196], sB2[196];       // [d3*14 + d5]
    __shared__ __align__(16) float sF1[2744], sF2[2744];   // [d3][ps]
    __shared__ __align__(16) float sG1[2744], sG2[2744];   // [d3][ps]

    const unsigned raw = blockIdx.x;
    const unsigned b   = (raw % NXCD) * BLK_PER_XCD + raw / NXCD;

    const unsigned d2 = b % 14u;
    const unsigned nq = b / 14u;
    const unsigned q  = nq % 20u;
    const unsigned n  = nq / 20u;

    const float* g    = in + (size_t)n * N_STRIDE;
    const float* cor1 = g;
    const float* cor2 = g + TSTRIDE;
    const float* cen1 = g + 2 * TSTRIDE;
    const float* cen2 = g + 3 * TSTRIDE;

    const unsigned tid = threadIdx.x;

    // ---- Pass 1: small tables (as R6) ----
    if (tid < 196u) {
        const unsigned ps = tid;
        sT1[ps] = cen1[ps] * cen1[(1u + q) * 196u + ps] * cen1[(23u + d2) * 196u + ps];
        sT2[ps] = cen2[ps] * cen2[(1u + q) * 196u + ps] * cen2[(23u + d2) * 196u + ps];
        const unsigned d3 = ps / 14u;
        const unsigned k  = ps - d3 * 14u;
        const unsigned pc = d2 * 14u + d3;
        const float k1 = 0.5f * cor1[pc] * cor1[(1u + q) * 196u + pc];
        const float k2 = 0.5f * cor2[pc] * cor2[(1u + q) * 196u + pc];
        sA1[ps] = k1 * cor1[(23u + k) * 196u + pc];
        sA2[ps] = k2 * cor2[(23u + k) * 196u + pc];
        sB1[ps] = cor1[(37u + k) * 196u + pc];
        sB2[ps] = cor2[(37u + k) * 196u + pc];
    }
    __syncthreads();

    // ---- Pass 2: materialize F and G tables ----
    for (unsigned c = tid; c < 686u; c += 256u) {
        const unsigned d3 = c / 49u;
        const unsigned f  = c - d3 * 49u;
        const unsigned e  = 4u * f;

        const float4 t1 = *(const float4*)&sT1[e];
        const float4 t2 = *(const float4*)&sT2[e];
        const float4 v1 = *(const float4*)&cen1[(37u + d3) * 196u + e];
        const float4 v2 = *(const float4*)&cen2[(37u + d3) * 196u + e];
        ((float4*)sG1)[c] = make_float4(t1.x * v1.x, t1.y * v1.y, t1.z * v1.z, t1.w * v1.w);
        ((float4*)sG2)[c] = make_float4(t2.x * v2.x, t2.y * v2.y, t2.z * v2.z, t2.w * v2.w);

        unsigned d4 = e / 14u;
        unsigned d5 = e - d4 * 14u;
        float F1[4], F2[4];
#pragma unroll
        for (int l = 0; l < 4; ++l) {
            F1[l] = sA1[d3 * 14u + d4] * sB1[d3 * 14u + d5];
            F2[l] = sA2[d3 * 14u + d4] * sB2[d3 * 14u + d5];
            ++d5;
            const unsigned carry = (d5 == 14u);
            d4 += carry;
            d5 = carry ? 0u : d5;
        }
        ((float4*)sF1)[c] = make_float4(F1[0], F1[1], F1[2], F1[3]);
        ((float4*)sF2)[c] = make_float4(F2[0], F2[1], F2[2], F2[3]);
    }
    __syncthreads();

    // ---- Main: pure LDS b128 -> mul -> store burst; zero global loads ----
    const size_t chunk = ((size_t)(n * 20u + q) * 196u + d2 * 14u) * 196u;
    float4* o1 = (float4*)(out + chunk);
    float4* o2 = (float4*)(out + (size_t)S_PER + chunk);
    float4* o3 = (float4*)(out + 2u * (size_t)S_PER + chunk);
    float4* o4 = (float4*)(out + 3u * (size_t)S_PER + chunk);

    for (unsigned c = tid; c < 686u; c += 256u) {
        const float4 F1 = ((const float4*)sF1)[c];
        const float4 F2 = ((const float4*)sF2)[c];
        const float4 G1 = ((const float4*)sG1)[c];
        const float4 G2 = ((const float4*)sG2)[c];

        o1[c] = make_float4(F1.x * G1.x, F1.y * G1.y, F1.z * G1.z, F1.w * G1.w);
        o2[c] = make_float4(F2.x * G1.x, F2.y * G1.y, F2.z * G1.z, F2.w * G1.w);
        o3[c] = make_float4(F1.x * G2.x, F1.y * G2.y, F1.z * G2.z, F1.w * G2.w);
        o4[c] = make_float4(F2.x * G2.x, F2.y * G2.y, F2.z * G2.z, F2.w * G2.w);
    }
}

extern "C" void kernel_launch(void* const* d_in, const int* in_sizes, int n_in,
                              void* d_out, int out_size, void* d_ws, size_t ws_size,
                              hipStream_t stream) {
    const float* in = (const float*)d_in[0];
    float* out = (float*)d_out;
    dim3 grid(NBLK);               // one block per (n, q, d2), XCD-remapped inside
    dim3 block(256);
    plnet_kernel<<<grid, block, 0, stream>>>(in, out);
}